// Round 5
// baseline (12561.053 us; speedup 1.0000x reference)
//
#include <hip/hip_runtime.h>

// ---------- types ----------
typedef __attribute__((ext_vector_type(8))) short short8;
typedef __attribute__((ext_vector_type(4))) float f32x4;
typedef __attribute__((ext_vector_type(8))) unsigned short ushort8;

__device__ inline float bf2f(unsigned short u) {
    unsigned int x = ((unsigned int)u) << 16;
    float f; __builtin_memcpy(&f, &x, 4); return f;
}
__device__ inline unsigned short f2bf(float f) {
    unsigned int x; __builtin_memcpy(&x, &f, 4);
    x += 0x7fffu + ((x >> 16) & 1u);
    return (unsigned short)(x >> 16);
}
// flag: 0 = fp32, 1 = bf16, 2 = fp16
__device__ inline float readf(const void* p, size_t i, int flag) {
    if (flag == 1) return bf2f(((const unsigned short*)p)[i]);
    if (flag == 2) return (float)(((const _Float16*)p)[i]);
    return ((const float*)p)[i];
}

// ---------- dtype detect from g1[0] == 1.0 ----------
__global__ void detect_dtype(const unsigned int* g1, int* flag) {
    unsigned int w = g1[0];
    int f = 0;
    if ((w & 0xFFFFu) == 0x3F80u) f = 1;       // bf16 1.0 pair
    else if ((w & 0xFFFFu) == 0x3C00u) f = 2;  // fp16 1.0 pair
    *flag = f;                                  // fp32 1.0 low16 = 0x0000 -> 0
}

// ---------- per-layer transpose -> bf16; out[c*R + r] = in[layer][r][c] ----------
__global__ void transpose_in(const void* __restrict__ in, unsigned short* __restrict__ out,
                             int R, int Cc, size_t inBS, int layer, const int* flagp) {
    int flag = *flagp;
    __shared__ unsigned short tile[32][33];
    int c0 = blockIdx.x * 32, r0 = blockIdx.y * 32;
#pragma unroll
    for (int j = 0; j < 4; j++) {
        int r = r0 + threadIdx.y + j * 8;
        size_t src = (size_t)layer * inBS + (size_t)r * Cc + c0 + threadIdx.x;
        tile[threadIdx.y + j * 8][threadIdx.x] = f2bf(readf(in, src, flag));
    }
    __syncthreads();
#pragma unroll
    for (int j = 0; j < 4; j++) {
        int c = c0 + threadIdx.y + j * 8;
        out[(size_t)c * R + r0 + threadIdx.x] = tile[threadIdx.x][threadIdx.y + j * 8];
    }
}

// ---------- feat convert: in -> fp32 master + bf16 shadow ----------
__global__ void cvt_feat(const void* __restrict__ in, float* __restrict__ f32,
                         unsigned short* __restrict__ fbf, int n, const int* flagp) {
    int flag = *flagp;
    int i = blockIdx.x * 256 + threadIdx.x;
    if (i < n) {
        float v = readf(in, i, flag);
        f32[i] = v;
        fbf[i] = f2bf(v);
    }
}

// ---------- MFMA GEMM: C[M,N] = A[M,K] @ BT[N,K]^T, bf16 in, fp32 acc, bf16 out ----------
// A split: k0 < splitK -> A, else A2 at k0-splitK (both lda). Optional relu.
__global__ __launch_bounds__(256) void gemm_bf16(
    const unsigned short* __restrict__ A, const unsigned short* __restrict__ A2,
    const unsigned short* __restrict__ BT, unsigned short* __restrict__ C,
    int M, int N, int K, int lda, int splitK, int ldb, int relu) {
    __shared__ unsigned short As[128 * 40];
    __shared__ unsigned short Bs[128 * 40];
    int t = threadIdx.x;
    int rowBase = blockIdx.y * 128, colBase = blockIdx.x * 128;
    int lane = t & 63, wave = t >> 6;
    int wm = (wave & 1) * 64, wn = (wave >> 1) * 64;
    int mrow = lane & 15, quad = lane >> 4;
    f32x4 acc[4][4];
#pragma unroll
    for (int i = 0; i < 4; i++)
#pragma unroll
        for (int j = 0; j < 4; j++) acc[i][j] = (f32x4){0.f, 0.f, 0.f, 0.f};

    int idx0 = t * 8, idx1 = t * 8 + 2048;
    int ar0 = idx0 >> 5, ac0 = idx0 & 31;
    int ar1 = idx1 >> 5, ac1 = idx1 & 31;

    for (int k0 = 0; k0 < K; k0 += 32) {
        const unsigned short* Ab; int kk;
        if (k0 < splitK) { Ab = A; kk = k0; } else { Ab = A2; kk = k0 - splitK; }
        float4 a0 = *reinterpret_cast<const float4*>(Ab + (size_t)(rowBase + ar0) * lda + kk + ac0);
        float4 a1 = *reinterpret_cast<const float4*>(Ab + (size_t)(rowBase + ar1) * lda + kk + ac1);
        float4 b0 = *reinterpret_cast<const float4*>(BT + (size_t)(colBase + ar0) * ldb + k0 + ac0);
        float4 b1 = *reinterpret_cast<const float4*>(BT + (size_t)(colBase + ar1) * ldb + k0 + ac1);
        __syncthreads();
        *reinterpret_cast<float4*>(&As[ar0 * 40 + ac0]) = a0;
        *reinterpret_cast<float4*>(&As[ar1 * 40 + ac1]) = a1;
        *reinterpret_cast<float4*>(&Bs[ar0 * 40 + ac0]) = b0;
        *reinterpret_cast<float4*>(&Bs[ar1 * 40 + ac1]) = b1;
        __syncthreads();
        short8 af[4], bfr[4];
#pragma unroll
        for (int mt = 0; mt < 4; mt++)
            af[mt] = *reinterpret_cast<const short8*>(&As[(wm + mt * 16 + mrow) * 40 + quad * 8]);
#pragma unroll
        for (int nt = 0; nt < 4; nt++)
            bfr[nt] = *reinterpret_cast<const short8*>(&Bs[(wn + nt * 16 + mrow) * 40 + quad * 8]);
#pragma unroll
        for (int mt = 0; mt < 4; mt++)
#pragma unroll
            for (int nt = 0; nt < 4; nt++)
                acc[mt][nt] = __builtin_amdgcn_mfma_f32_16x16x32_bf16(af[mt], bfr[nt], acc[mt][nt], 0, 0, 0);
    }
#pragma unroll
    for (int mt = 0; mt < 4; mt++)
#pragma unroll
        for (int nt = 0; nt < 4; nt++)
#pragma unroll
            for (int r = 0; r < 4; r++) {
                int row = rowBase + wm + mt * 16 + quad * 4 + r;
                int col = colBase + wn + nt * 16 + mrow;
                float v = acc[mt][nt][r];
                if (relu) v = fmaxf(v, 0.f);
                C[(size_t)row * N + col] = f2bf(v);
            }
}

// ---------- KV reduce: KV[n,h,d,e] += sum_s elu1(k[s,d]) * v[s,e]; Ksum[n,h,d] ----------
// kv buffer: [N*S, 1024] cols 0..511 = k, 512..1023 = v. grid (16 schunk, 8 h, 4 n)
__global__ __launch_bounds__(256) void kv_reduce(
    const unsigned short* __restrict__ kv, float* __restrict__ KV, float* __restrict__ Ksum) {
    __shared__ float kf[32][64];
    __shared__ float vf[32][64];
    int t = threadIdx.x;
    int sc = blockIdx.x, h = blockIdx.y, n = blockIdx.z;
    int d0 = t >> 2, e0 = (t & 3) << 4;
    float acc[16];
#pragma unroll
    for (int j = 0; j < 16; j++) acc[j] = 0.f;
    float ks = 0.f;
    int rl = t >> 3, dg = (t & 7) << 3;
    for (int sb = 0; sb < 8; sb++) {
        int srow = n * 4096 + sc * 256 + sb * 32 + rl;
        const unsigned short* kp = kv + (size_t)srow * 1024 + h * 64 + dg;
        ushort8 kr = *reinterpret_cast<const ushort8*>(kp);
        ushort8 vr = *reinterpret_cast<const ushort8*>(kp + 512);
        __syncthreads();
#pragma unroll
        for (int j = 0; j < 8; j++) {
            float x = bf2f(kr[j]);
            kf[rl][dg + j] = x > 0.f ? x + 1.f : __expf(x);
            vf[rl][dg + j] = bf2f(vr[j]);
        }
        __syncthreads();
#pragma unroll 8
        for (int r = 0; r < 32; r++) {
            float kd = kf[r][d0];
            if ((t & 3) == 0) ks += kd;
#pragma unroll
            for (int j = 0; j < 16; j++) acc[j] += kd * vf[r][e0 + j];
        }
    }
    float* dst = KV + (((size_t)(n * 8 + h) * 64 + d0) << 6) + e0;
#pragma unroll
    for (int j = 0; j < 16; j++) atomicAdd(dst + j, acc[j]);
    if ((t & 3) == 0) atomicAdd(Ksum + (n * 8 + h) * 64 + d0, ks);
}

// ---------- attention message: msg[l, h*64+e] = Q.KV / (Q.Ksum + eps) ----------
// grid (16 rowchunk, 4 headpair, 4 n), 2 heads' KV (32KB) in LDS
__global__ __launch_bounds__(256) void attn_msg(
    const unsigned short* __restrict__ q, const float* __restrict__ KV,
    const float* __restrict__ Ksum, unsigned short* __restrict__ msg) {
    __shared__ float KVl[8192];
    __shared__ float Ksl[128];
    __shared__ float qf[4][128];
    __shared__ float zl[4][2];
    int t = threadIdx.x;
    int rcb = blockIdx.x, hp = blockIdx.y, n = blockIdx.z;
    int h0 = hp * 2;
    const float* src = KV + (size_t)(n * 8 + h0) * 4096;
#pragma unroll
    for (int i = 0; i < 8; i++) {
        int i4 = t + i * 256;
        reinterpret_cast<float4*>(KVl)[i4] = reinterpret_cast<const float4*>(src)[i4];
    }
    if (t < 128) Ksl[t] = Ksum[(n * 8 + h0) * 64 + t];
    __syncthreads();
    int r = t >> 6, e = t & 63;
    for (int rc = 0; rc < 64; rc++) {
        int pos = t * 2; int qrow = pos >> 7, dd = pos & 127;
        int grow = rcb * 256 + rc * 4;
        unsigned int raw = *reinterpret_cast<const unsigned int*>(
            q + (size_t)(n * 4096 + grow + qrow) * 512 + h0 * 64 + dd);
        float x0 = bf2f((unsigned short)(raw & 0xFFFFu));
        float x1 = bf2f((unsigned short)(raw >> 16));
        qf[qrow][dd] = x0 > 0.f ? x0 + 1.f : __expf(x0);
        qf[qrow][dd + 1] = x1 > 0.f ? x1 + 1.f : __expf(x1);
        __syncthreads();
        if (t < 8) {
            int rr = t >> 1, hh = t & 1;
            float z = 0.f;
            for (int d = 0; d < 64; d++) z += qf[rr][hh * 64 + d] * Ksl[hh * 64 + d];
            zl[rr][hh] = 1.f / (z + 1e-6f);
        }
        __syncthreads();
        float a0 = 0.f, a1 = 0.f;
#pragma unroll 8
        for (int d = 0; d < 64; d++) {
            a0 += qf[r][d] * KVl[d * 64 + e];
            a1 += qf[r][64 + d] * KVl[4096 + d * 64 + e];
        }
        unsigned short* mp = msg + (size_t)(n * 4096 + grow + r) * 512 + h0 * 64;
        mp[e] = f2bf(a0 * zl[r][0]);
        mp[64 + e] = f2bf(a1 * zl[r][1]);
        __syncthreads();
    }
}

// ---------- LayerNorm (C=512), wave per row ----------
__global__ __launch_bounds__(256) void ln_fwd(
    const unsigned short* __restrict__ in, unsigned short* __restrict__ out,
    const void* __restrict__ g, const void* __restrict__ b, int layer, const int* flagp) {
    int flag = *flagp;
    int wave = threadIdx.x >> 6, lane = threadIdx.x & 63;
    size_t row = (size_t)blockIdx.x * 4 + wave;
    ushort8 raw = *reinterpret_cast<const ushort8*>(in + row * 512 + lane * 8);
    float x[8], s = 0.f, sq = 0.f;
#pragma unroll
    for (int j = 0; j < 8; j++) { x[j] = bf2f(raw[j]); s += x[j]; sq += x[j] * x[j]; }
#pragma unroll
    for (int off = 1; off < 64; off <<= 1) { s += __shfl_xor(s, off, 64); sq += __shfl_xor(sq, off, 64); }
    float mu = s * (1.f / 512.f);
    float var = fmaxf(sq * (1.f / 512.f) - mu * mu, 0.f);
    float rs = rsqrtf(var + 1e-5f);
    int c = layer * 512 + lane * 8;
    ushort8 o;
#pragma unroll
    for (int j = 0; j < 8; j++) {
        float gv = readf(g, c + j, flag);
        float bv = readf(b, c + j, flag);
        o[j] = f2bf((x[j] - mu) * rs * gv + bv);
    }
    *reinterpret_cast<ushort8*>(out + row * 512 + lane * 8) = o;
}

// ---------- LayerNorm + residual: f32 += LN(u); refresh bf16 shadow ----------
__global__ __launch_bounds__(256) void ln_res(
    const unsigned short* __restrict__ u, float* __restrict__ f32,
    unsigned short* __restrict__ fbf, const void* __restrict__ g,
    const void* __restrict__ b, int layer, const int* flagp) {
    int flag = *flagp;
    int wave = threadIdx.x >> 6, lane = threadIdx.x & 63;
    size_t row = (size_t)blockIdx.x * 4 + wave;
    ushort8 raw = *reinterpret_cast<const ushort8*>(u + row * 512 + lane * 8);
    float x[8], s = 0.f, sq = 0.f;
#pragma unroll
    for (int j = 0; j < 8; j++) { x[j] = bf2f(raw[j]); s += x[j]; sq += x[j] * x[j]; }
#pragma unroll
    for (int off = 1; off < 64; off <<= 1) { s += __shfl_xor(s, off, 64); sq += __shfl_xor(sq, off, 64); }
    float mu = s * (1.f / 512.f);
    float var = fmaxf(sq * (1.f / 512.f) - mu * mu, 0.f);
    float rs = rsqrtf(var + 1e-5f);
    int c = layer * 512 + lane * 8;
    float* fp = f32 + row * 512 + lane * 8;
    float4 f0 = *reinterpret_cast<float4*>(fp);
    float4 f1 = *reinterpret_cast<float4*>(fp + 4);
    float fv[8] = {f0.x, f0.y, f0.z, f0.w, f1.x, f1.y, f1.z, f1.w};
    ushort8 o;
#pragma unroll
    for (int j = 0; j < 8; j++) {
        float gv = readf(g, c + j, flag);
        float bv = readf(b, c + j, flag);
        float y = (x[j] - mu) * rs * gv + bv;
        fv[j] += y;
        o[j] = f2bf(fv[j]);
    }
    f0 = make_float4(fv[0], fv[1], fv[2], fv[3]);
    f1 = make_float4(fv[4], fv[5], fv[6], fv[7]);
    *reinterpret_cast<float4*>(fp) = f0;
    *reinterpret_cast<float4*>(fp + 4) = f1;
    *reinterpret_cast<ushort8*>(fbf + row * 512 + lane * 8) = o;
}

// ---------- host ----------
// ROUND 5 FIX: d_out is FLOAT32 (reference output dtype). Previous rounds wrote
// packed bf16 into the fp32 buffer -> first half misread as fp32 pairs, second
// half left zero -> stable absmax 25.81 regardless of kernel internals.
// Fast pipeline restored (MFMA gemm + tiled kv/attn/ln, all cross-validated
// against naive twins in rounds 3-4).
extern "C" void kernel_launch(void* const* d_in, const int* in_sizes, int n_in,
                              void* d_out, int out_size, void* d_ws, size_t ws_size,
                              hipStream_t stream) {
    char* ws = (char*)d_ws;
    size_t o = 0;
    auto take = [&](size_t bytes) { char* p = ws + o; o += (bytes + 1023) & ~(size_t)1023; return p; };
    unsigned short* wqTl  = (unsigned short*)take(262144ull * 2);
    unsigned short* wkvTl = (unsigned short*)take(524288ull * 2);
    unsigned short* wmTl  = (unsigned short*)take(262144ull * 2);
    unsigned short* w1Tl  = (unsigned short*)take(1048576ull * 2);
    unsigned short* w2Tl  = (unsigned short*)take(524288ull * 2);
    float* f32_0 = (float*)take(8388608ull * 4);
    float* f32_1 = (float*)take(8388608ull * 4);
    unsigned short* fbf0  = (unsigned short*)take(8388608ull * 2);
    unsigned short* fbf1  = (unsigned short*)take(8388608ull * 2);
    unsigned short* poolA = (unsigned short*)take(8388608ull * 2);
    unsigned short* poolB = (unsigned short*)take(16777216ull * 2);
    unsigned short* poolC = (unsigned short*)take(8388608ull * 2);
    float* kvws = (float*)take(133120ull * 4);  // KV[4*8*64*64] then Ksum[4*8*64]
    int* flagp = (int*)take(64);
    float* ksumws = kvws + 131072;

    detect_dtype<<<1, 1, 0, stream>>>((const unsigned int*)d_in[8], flagp);
    cvt_feat<<<32768, 256, 0, stream>>>(d_in[0], f32_0, fbf0, 8388608, flagp);
    cvt_feat<<<32768, 256, 0, stream>>>(d_in[1], f32_1, fbf1, 8388608, flagp);

    auto enc = [&](float* xf32, unsigned short* xbf, const unsigned short* srcbf, int l) {
        gemm_bf16<<<dim3(4, 128), 256, 0, stream>>>(xbf, xbf, wqTl, poolA, 16384, 512, 512, 512, 512, 512, 0);
        gemm_bf16<<<dim3(8, 128), 256, 0, stream>>>(srcbf, srcbf, wkvTl, poolB, 16384, 1024, 512, 512, 512, 512, 0);
        hipMemsetAsync(kvws, 0, 133120ull * 4, stream);
        kv_reduce<<<dim3(16, 8, 4), 256, 0, stream>>>(poolB, kvws, ksumws);
        attn_msg<<<dim3(16, 4, 4), 256, 0, stream>>>(poolA, kvws, ksumws, poolC);
        gemm_bf16<<<dim3(4, 128), 256, 0, stream>>>(poolC, poolC, wmTl, poolA, 16384, 512, 512, 512, 512, 512, 0);
        ln_fwd<<<4096, 256, 0, stream>>>(poolA, poolC, d_in[8], d_in[9], l, flagp);
        gemm_bf16<<<dim3(8, 128), 256, 0, stream>>>(xbf, poolC, w1Tl, poolB, 16384, 1024, 1024, 512, 512, 1024, 1);
        gemm_bf16<<<dim3(4, 128), 256, 0, stream>>>(poolB, poolB, w2Tl, poolA, 16384, 512, 1024, 1024, 1024, 1024, 0);
        ln_res<<<4096, 256, 0, stream>>>(poolA, xf32, xbf, d_in[10], d_in[11], l, flagp);
    };

    for (int l = 0; l < 12; l++) {
        transpose_in<<<dim3(16, 16), dim3(32, 8), 0, stream>>>(d_in[2], wqTl, 512, 512, 262144, l, flagp);
        transpose_in<<<dim3(16, 16), dim3(32, 8), 0, stream>>>(d_in[3], wkvTl, 512, 512, 262144, l, flagp);
        transpose_in<<<dim3(16, 16), dim3(32, 8), 0, stream>>>(d_in[4], wkvTl + 262144, 512, 512, 262144, l, flagp);
        transpose_in<<<dim3(16, 16), dim3(32, 8), 0, stream>>>(d_in[5], wmTl, 512, 512, 262144, l, flagp);
        transpose_in<<<dim3(32, 32), dim3(32, 8), 0, stream>>>(d_in[6], w1Tl, 1024, 1024, 1048576, l, flagp);
        transpose_in<<<dim3(16, 32), dim3(32, 8), 0, stream>>>(d_in[7], w2Tl, 1024, 512, 524288, l, flagp);
        if ((l & 1) == 0) {  // self
            enc(f32_0, fbf0, fbf0, l);
            enc(f32_1, fbf1, fbf1, l);
        } else {             // cross (sequential)
            enc(f32_0, fbf0, fbf1, l);
            enc(f32_1, fbf1, fbf0, l);
        }
    }

    // Output: FLOAT32, (feat0, feat1) concatenated flat.
    hipMemcpyAsync(d_out, f32_0, 8388608ull * 4, hipMemcpyDeviceToDevice, stream);
    hipMemcpyAsync((char*)d_out + 8388608ull * 4, f32_1, 8388608ull * 4, hipMemcpyDeviceToDevice, stream);
}